// Round 5
// baseline (91.385 us; speedup 1.0000x reference)
//
#include <hip/hip_runtime.h>
#include <hip/hip_bf16.h>
#include <math.h>

#define T_TRACKS 1024
#define HIDDEN 128
#define LATENT 16
#define NGRID 16
#define NCELLS 256
#define KDIM 4096
#define OUTD 128

typedef unsigned short ushort_t;
typedef __attribute__((ext_vector_type(8))) short frag_ab;   // 8 bf16
typedef __attribute__((ext_vector_type(4))) float f32x4;

static __device__ inline ushort_t f2bf(float x) {
    __hip_bfloat16 h = __float2bfloat16(x);
    return *reinterpret_cast<ushort_t*>(&h);
}

// ---------------- ws layout (byte offsets) ----------------
// vals_bf16 [1024][16]             @ 0         (32 KB)
// W_t bf16 [128 o][4096 k]         @ 32768     (1 MB)
// occ bf16 [1024][4096]            @ 1081344   (8 MB)
// partial f32 [32 kt][1024][128]   @ 9469952   (16 MB)
#define WS_VALS 0
#define WS_WT   32768
#define WS_OCC  1081344
#define WS_PART 9469952
#define WS_NEED (9469952 + 33554432/2)

// ============ K1: prep (vals bf16 | W_emb transpose->bf16) ============
__global__ __launch_bounds__(256) void prep_kernel(const float* __restrict__ hidden,
                                                   const float* __restrict__ W_enc,
                                                   const float* __restrict__ b_enc,
                                                   const float* __restrict__ W_emb,
                                                   ushort_t* __restrict__ vals_bf16,
                                                   ushort_t* __restrict__ W_t) {
    const int b = blockIdx.x;
    const int tid = threadIdx.x;
    if (b < 64) {
        // vals[j][l] = hidden[j] @ W_enc[:,l] + b_enc[l]  -> bf16
        int idx = b * 256 + tid;           // 0..16383
        int j = idx >> 4, l = idx & 15;
        const float* h = hidden + j * HIDDEN;
        float acc = b_enc[l];
#pragma unroll 8
        for (int k = 0; k < HIDDEN; k++) acc += h[k] * W_enc[k * LATENT + l];
        vals_bf16[idx] = f2bf(acc);
    } else {
        // W_t[o][k] = bf16(W_emb[k][o]); thread handles (o, 8 consecutive k)
        int idx = (b - 64) * 256 + tid;    // 0..65535
        int kc = idx >> 7;                 // 0..511 (chunk of 8 k)
        int o = idx & 127;
        ushort_t tmp[8];
#pragma unroll
        for (int u = 0; u < 8; u++) tmp[u] = f2bf(W_emb[(kc * 8 + u) * OUTD + o]);
        *reinterpret_cast<uint4*>(W_t + o * KDIM + kc * 8) = *reinterpret_cast<uint4*>(tmp);
    }
}

// ============ K2: build occ rows (bf16, k = l*256 + c order) ============
__global__ __launch_bounds__(256) void occ_kernel(const float* __restrict__ obs2,
                                                  const ushort_t* __restrict__ vals_bf16,
                                                  ushort_t* __restrict__ occ) {
    const int i = blockIdx.x;
    const int tid = threadIdx.x;
    __shared__ int owner[NCELLS];
    __shared__ ushort_t socc[LATENT * NCELLS];   // [l][c], 8 KB
    owner[tid] = -1;

    float oix = obs2[i * 2 + 0];
    float oiy = obs2[i * 2 + 1];
    if (isnan(oix) || isnan(oiy)) { oix = 0.0f; oiy = 0.0f; }
    __syncthreads();

    for (int j = tid; j < T_TRACKS; j += 256) {
        if (j == i) continue;
        float ox = obs2[j * 2 + 0];
        float oy = obs2[j * 2 + 1];
        if (isnan(ox) || isnan(oy)) { ox = 0.0f; oy = 0.0f; }
        float gx = (ox - oix) * 0.5f + 8.0f;
        float gy = (oy - oiy) * 0.5f + 8.0f;
        bool inr = (gx >= 0.0f) && (gx < 16.0f) && (gy >= 0.0f) && (gy < 16.0f);
        int c = inr ? ((int)gx * NGRID + (int)gy) : 0;   // OOR scatters 0 into cell 0
        atomicMax(&owner[c], j);
    }
    __syncthreads();

    {
        const int c = tid;
        int j = owner[c];
        bool valid = (j >= 0);
        if (c == 0 && valid) {
            // cell 0's winner may be an out-of-range neighbor (value 0)
            float ox = obs2[j * 2 + 0];
            float oy = obs2[j * 2 + 1];
            if (isnan(ox) || isnan(oy)) { ox = 0.0f; oy = 0.0f; }
            float gx = (ox - oix) * 0.5f + 8.0f;
            float gy = (oy - oiy) * 0.5f + 8.0f;
            valid = (gx >= 0.0f) && (gx < 16.0f) && (gy >= 0.0f) && (gy < 16.0f);
        }
        int jj = (j >= 0) ? j : 0;
        ushort_t vv[16];
        *reinterpret_cast<uint4*>(vv)     = *reinterpret_cast<const uint4*>(vals_bf16 + jj * LATENT);
        *reinterpret_cast<uint4*>(vv + 8) = *reinterpret_cast<const uint4*>(vals_bf16 + jj * LATENT + 8);
#pragma unroll
        for (int l = 0; l < LATENT; l++) {
            socc[l * NCELLS + c] = valid ? vv[l] : (ushort_t)0;
        }
    }
    __syncthreads();

    // coalesced store of the 4096-elem row (512 uint4, 2 per thread)
    uint4* dst = reinterpret_cast<uint4*>(occ + i * KDIM);
    const uint4* src = reinterpret_cast<const uint4*>(socc);
    dst[tid]       = src[tid];
    dst[tid + 256] = src[tid + 256];
}

// ============ K3: MFMA GEMM, Kseg=128, grid 512 (3 blocks/CU co-resident) ============
// kt = blockIdx & 31 (Kseg=128), mt = blockIdx >> 5 (Mtile=64)
#define BK 128
#define LDSTR 136   // row stride in bf16 elems (128 + 8 pad)
__global__ __launch_bounds__(256) void gemm_kernel(const ushort_t* __restrict__ occ,
                                                   const ushort_t* __restrict__ W_t,
                                                   float* __restrict__ partial) {
    const int tid = threadIdx.x;
    const int kt = blockIdx.x & 31;
    const int mt = blockIdx.x >> 5;
    const int wave = tid >> 6;
    const int lane = tid & 63;
    const int lrow = lane & 15;
    const int quad = lane >> 4;

    __shared__ ushort_t As[64 * LDSTR];    // 17408 B
    __shared__ ushort_t Bs[128 * LDSTR];   // 34816 B  (52 KB total -> 3 blocks/CU)

    f32x4 acc[8];
#pragma unroll
    for (int nt = 0; nt < 8; nt++) acc[nt] = (f32x4){0.f, 0.f, 0.f, 0.f};

    const int k0 = kt * BK;
    // stage A: 64 rows x 128 k = 1024 16B-granules
    for (int g = tid; g < 1024; g += 256) {
        int r = g >> 4, cs = g & 15;
        uint4 v = *reinterpret_cast<const uint4*>(occ + (mt * 64 + r) * KDIM + k0 + cs * 8);
        *reinterpret_cast<uint4*>(As + r * LDSTR + cs * 8) = v;
    }
    // stage B: 128 rows x 128 k = 2048 granules
    for (int g = tid; g < 2048; g += 256) {
        int n = g >> 4, cs = g & 15;
        uint4 v = *reinterpret_cast<const uint4*>(W_t + n * KDIM + k0 + cs * 8);
        *reinterpret_cast<uint4*>(Bs + n * LDSTR + cs * 8) = v;
    }
    __syncthreads();
#pragma unroll
    for (int ks = 0; ks < 4; ks++) {   // K=32 per mfma, 4 steps = 128
        const int koff = ks * 32 + quad * 8;
        frag_ab a = *reinterpret_cast<const frag_ab*>(&As[(wave * 16 + lrow) * LDSTR + koff]);
#pragma unroll
        for (int nt = 0; nt < 8; nt++) {
            frag_ab bfr = *reinterpret_cast<const frag_ab*>(&Bs[(nt * 16 + lrow) * LDSTR + koff]);
            acc[nt] = __builtin_amdgcn_mfma_f32_16x16x32_bf16(a, bfr, acc[nt], 0, 0, 0);
        }
    }
    // C/D layout: col = lane&15, row = quad*4+reg (m89/m91-verified)
    float* pt = partial + (size_t)kt * (T_TRACKS * OUTD) + (mt * 64) * OUTD;
#pragma unroll
    for (int nt = 0; nt < 8; nt++) {
        int n = nt * 16 + lrow;
#pragma unroll
        for (int reg = 0; reg < 4; reg++) {
            int m = wave * 16 + quad * 4 + reg;
            pt[m * OUTD + n] = acc[nt][reg];
        }
    }
}

// ============ K4: reduce 32 partials + bias + relu ============
__global__ __launch_bounds__(256) void reduce_kernel(const float* __restrict__ partial,
                                                     const float* __restrict__ b_emb,
                                                     float* __restrict__ out) {
    int idx = blockIdx.x * 256 + threadIdx.x;   // 0..32767 (float4 groups of [1024][128])
    const float4* p4 = reinterpret_cast<const float4*>(partial);
    float4 s = p4[idx];
#pragma unroll
    for (int kt = 1; kt < 32; kt++) {
        float4 v = p4[kt * 32768 + idx];
        s.x += v.x; s.y += v.y; s.z += v.z; s.w += v.w;
    }
    float4 bv = reinterpret_cast<const float4*>(b_emb)[idx & 31];
    float4 r;
    r.x = fmaxf(s.x + bv.x, 0.0f);
    r.y = fmaxf(s.y + bv.y, 0.0f);
    r.z = fmaxf(s.z + bv.z, 0.0f);
    r.w = fmaxf(s.w + bv.w, 0.0f);
    reinterpret_cast<float4*>(out)[idx] = r;
}

// ================= Round-1 fallback (f32, fused) for small ws =================
__global__ __launch_bounds__(256) void vals_kernel_f32(const float* __restrict__ hidden,
                                                       const float* __restrict__ W_enc,
                                                       const float* __restrict__ b_enc,
                                                       float* __restrict__ vals) {
    int idx = blockIdx.x * 256 + threadIdx.x;
    int j = idx >> 4, l = idx & 15;
    const float* h = hidden + j * HIDDEN;
    float acc = b_enc[l];
#pragma unroll 8
    for (int k = 0; k < HIDDEN; k++) acc += h[k] * W_enc[k * LATENT + l];
    vals[idx] = acc;
}

__global__ __launch_bounds__(256) void pool_kernel_f32(const float* __restrict__ obs2,
                                                       const float* __restrict__ vals,
                                                       const float* __restrict__ W_emb,
                                                       const float* __restrict__ b_emb,
                                                       float* __restrict__ out) {
    const int i = blockIdx.x;
    const int tid = threadIdx.x;
    __shared__ int owner[NCELLS];
    __shared__ float occ[NCELLS * LATENT];
    __shared__ float partial[OUTD];
    owner[tid] = -1;
    float oix = obs2[i * 2 + 0];
    float oiy = obs2[i * 2 + 1];
    if (isnan(oix) || isnan(oiy)) { oix = 0.0f; oiy = 0.0f; }
    __syncthreads();
    for (int j = tid; j < T_TRACKS; j += 256) {
        if (j == i) continue;
        float ox = obs2[j * 2 + 0], oy = obs2[j * 2 + 1];
        if (isnan(ox) || isnan(oy)) { ox = 0.0f; oy = 0.0f; }
        float gx = (ox - oix) * 0.5f + 8.0f;
        float gy = (oy - oiy) * 0.5f + 8.0f;
        bool inr = (gx >= 0.0f) && (gx < 16.0f) && (gy >= 0.0f) && (gy < 16.0f);
        int c = inr ? ((int)gx * NGRID + (int)gy) : 0;
        atomicMax(&owner[c], j);
    }
    __syncthreads();
    {
        int j = owner[tid];
        bool valid = false;
        if (j >= 0) {
            float ox = obs2[j * 2 + 0], oy = obs2[j * 2 + 1];
            if (isnan(ox) || isnan(oy)) { ox = 0.0f; oy = 0.0f; }
            float gx = (ox - oix) * 0.5f + 8.0f;
            float gy = (oy - oiy) * 0.5f + 8.0f;
            valid = (gx >= 0.0f) && (gx < 16.0f) && (gy >= 0.0f) && (gy < 16.0f);
        }
        const float* vj = vals + (j >= 0 ? j : 0) * LATENT;
#pragma unroll
        for (int l = 0; l < LATENT; l++) occ[tid * LATENT + l] = valid ? vj[l] : 0.0f;
    }
    __syncthreads();
    const int o = tid & (OUTD - 1);
    const int half = tid >> 7;
    const int cbase = half * 128;
    float acc = 0.0f;
    for (int c = cbase; c < cbase + 128; c++) {
#pragma unroll
        for (int l = 0; l < LATENT; l++)
            acc += occ[c * LATENT + l] * W_emb[(l * NCELLS + c) * OUTD + o];
    }
    if (half == 0) partial[o] = acc;
    __syncthreads();
    if (half == 1) out[i * OUTD + o] = fmaxf(acc + partial[o] + b_emb[o], 0.0f);
}

extern "C" void kernel_launch(void* const* d_in, const int* in_sizes, int n_in,
                              void* d_out, int out_size, void* d_ws, size_t ws_size,
                              hipStream_t stream) {
    const float* hidden = (const float*)d_in[0];   // [1024,128]
    const float* obs2   = (const float*)d_in[2];   // [1024,2]
    const float* W_enc  = (const float*)d_in[3];   // [128,16]
    const float* b_enc  = (const float*)d_in[4];   // [16]
    const float* W_emb  = (const float*)d_in[5];   // [4096,128]
    const float* b_emb  = (const float*)d_in[6];   // [128]
    float* out = (float*)d_out;                    // [1024,128]

    if (ws_size < (size_t)WS_NEED) {
        // fallback: round-1 verified f32 path
        float* vals = (float*)d_ws;
        vals_kernel_f32<<<(T_TRACKS * LATENT) / 256, 256, 0, stream>>>(hidden, W_enc, b_enc, vals);
        pool_kernel_f32<<<T_TRACKS, 256, 0, stream>>>(obs2, vals, W_emb, b_emb, out);
        return;
    }

    char* ws = (char*)d_ws;
    ushort_t* vals_bf16 = (ushort_t*)(ws + WS_VALS);
    ushort_t* W_t       = (ushort_t*)(ws + WS_WT);
    ushort_t* occ       = (ushort_t*)(ws + WS_OCC);
    float*    partial   = (float*)(ws + WS_PART);

    prep_kernel<<<320, 256, 0, stream>>>(hidden, W_enc, b_enc, W_emb, vals_bf16, W_t);
    occ_kernel<<<T_TRACKS, 256, 0, stream>>>(obs2, vals_bf16, occ);
    gemm_kernel<<<512, 256, 0, stream>>>(occ, W_t, partial);
    reduce_kernel<<<128, 256, 0, stream>>>(partial, b_emb, out);
}